// Round 12
// baseline (895.644 us; speedup 1.0000x reference)
//
#include <hip/hip_runtime.h>

#define TT 512

typedef _Float16 h2_t  __attribute__((ext_vector_type(2)));
typedef _Float16 f16x4 __attribute__((ext_vector_type(4)));
typedef float    f32x4 __attribute__((ext_vector_type(4)));
typedef float    f32x4u __attribute__((ext_vector_type(4), aligned(4)));
typedef unsigned int u32x2_t __attribute__((ext_vector_type(2)));

__device__ __forceinline__ float frcp(float x){ return __builtin_amdgcn_rcpf(x); }
__device__ __forceinline__ float frsq(float x){ return __builtin_amdgcn_rsqf(x); }
__device__ __forceinline__ float sigm(float x){ return frcp(1.0f + __expf(-x)); }
__device__ __forceinline__ float tanh_fast(float x){
    x = fminf(15.0f, fmaxf(-15.0f, x));
    float e = __expf(2.0f * x);
    return (e - 1.0f) * frcp(e + 1.0f);
}
__device__ __forceinline__ float fdot2(h2_t a, h2_t b, float c){
    return __builtin_amdgcn_fdot2(a, b, c, false);
}
__device__ __forceinline__ h2_t pk16(float a, float b){
    return __builtin_bit_cast(h2_t, __builtin_amdgcn_cvt_pkrtz(a, b));
}
__device__ __forceinline__ f16x4 mk4(float a, float b, float c, float d){
    u32x2_t u;
    u[0] = __builtin_bit_cast(unsigned int, pk16(a, b));
    u[1] = __builtin_bit_cast(unsigned int, pk16(c, d));
    return __builtin_bit_cast(f16x4, u);
}
__device__ __forceinline__ f32x4 mfma16(f16x4 a, f16x4 b, f32x4 c){
    return __builtin_amdgcn_mfma_f32_16x16x16f16(a, b, c, 0, 0, 0);
}

// lgkmcnt-only barrier (R9-verified, 630us).  Only cross-wave traffic is
// LDS; vmcnt drain (as in __syncthreads) is unnecessary.
#define BARRIER() do { asm volatile("s_waitcnt lgkmcnt(0)" ::: "memory"); \
                       __builtin_amdgcn_s_barrier();                      \
                       asm volatile("" ::: "memory"); } while (0)

// R9 VERIFIED STRUCTURE (630 us) + dq hoist + fc 2x2 ONLY.
// HARD RULE from R3/4/5/R11 bisection: the K exchange MUST be the R9 form
// (two b32 writes to s_Kp[24][16], 18 b32 broadcast reads).  Every kernel
// that packed K pairs into one b64 LDS write + wide reads failed
// deterministically (264.5 with cast [16][20]; 206.0 with native [12][16])
// regardless of barrier type or loop structure; both b32 variants pass.
// Mechanism unidentified; form condemned empirically (4 fails, 5 passes).
//  - dq hoist: dq=normalize(1,gyro*dt/2) is input-only; step t+1's dq is
//    computed right after the nxt[] prefetch (fills stalls), removing the
//    ~10-op rsq prefix from the head's dependent chain.
//  - fc 2x2: the 4-deep fc MFMA C-in chain becomes two 2-deep chains +
//    one f32x4 add (FP reassociation only).
//
// 4 waves/block, 16 batch elems/block, M-split: wave w owns h rows
// 16w..16w+15 (gate tiles {w,4+w,8+w}); 1024 waves = every SIMD occupied.
// Edit 1 (kept): whh MFMAs issue at loop top against hB=h_{t-1}.
// h_new D-fragment of wave w IS B-fragment tile kt=w: no transpose.
// Scalar phase replicates across waves; only wave 0 stores.
__global__
__attribute__((amdgpu_flat_work_group_size(256, 256), amdgpu_waves_per_eu(1, 1)))
void kalman_kernel(const float* __restrict__ inputs,
                   const float* __restrict__ ln_gamma,
                   const float* __restrict__ ln_beta,
                   const float* __restrict__ w_ih,
                   const float* __restrict__ w_hh,
                   const float* __restrict__ b_ih,
                   const float* __restrict__ b_hh,
                   const float* __restrict__ fc_w,
                   const float* __restrict__ fc_b,
                   float* __restrict__ out)
{
    __shared__ u32x2_t     s_h[4][64];    // h_new B-fragments, per kt tile
    __shared__ unsigned int s_Kp[24][16]; // K row-pairs (f16x2) x batch col [b32 form - mandatory]

    const int tid  = threadIdx.x;
    const int lane = tid & 63;
    const int w    = tid >> 6;            // wave id = M-slice owner
    const int bq   = lane & 15;           // batch col / A row
    const int g    = lane >> 4;           // k-quad group
    const int e    = blockIdx.x * 16 + bq;

    const int mtR = w, mtZ = 4 + w, mtN = 8 + w;

    // ---- pinned A-fragments (f16), this wave's M-slice only ----
    f16x4 whhR[4], whhZ[4], whhN[4];
#pragma unroll
    for (int kt = 0; kt < 4; ++kt) {
        const float* rR = w_hh + (size_t)(16 * mtR + bq) * 64 + 16 * kt + 4 * g;
        const float* rZ = w_hh + (size_t)(16 * mtZ + bq) * 64 + 16 * kt + 4 * g;
        const float* rN = w_hh + (size_t)(16 * mtN + bq) * 64 + 16 * kt + 4 * g;
        whhR[kt] = mk4(rR[0], rR[1], rR[2], rR[3]);
        whhZ[kt] = mk4(rZ[0], rZ[1], rZ[2], rZ[3]);
        whhN[kt] = mk4(rN[0], rN[1], rN[2], rN[3]);
    }

    f16x4 wihR, wihZ, wihN;               // K=13 padded to 16
    {
        const float* rR = w_ih + (size_t)(16 * mtR + bq) * 13;
        const float* rZ = w_ih + (size_t)(16 * mtZ + bq) * 13;
        const float* rN = w_ih + (size_t)(16 * mtN + bq) * 13;
        const int k0 = 4 * g;
        const float m1 = (k0 + 1 < 13) ? 1.f : 0.f;
        const float m2 = (k0 + 2 < 13) ? 1.f : 0.f;
        const float m3 = (k0 + 3 < 13) ? 1.f : 0.f;
        wihR = mk4(rR[k0], m1 * rR[k0 + 1], m2 * rR[k0 + 2], m3 * rR[k0 + 3]);
        wihZ = mk4(rZ[k0], m1 * rZ[k0 + 1], m2 * rZ[k0 + 2], m3 * rZ[k0 + 3]);
        wihN = mk4(rN[k0], m1 * rN[k0 + 1], m2 * rN[k0 + 2], m3 * rN[k0 + 3]);
    }

    f16x4 fcA[4];                         // fc tile mt=w (rows >=36 masked)
    {
        const int o = 16 * w + bq;
        const float* rp = fc_w + (size_t)(o < 36 ? o : 0) * 64;
        const float msk = (o < 36) ? 1.f : 0.f;
#pragma unroll
        for (int kt = 0; kt < 4; ++kt) {
            const float* cp = rp + 16 * kt + 4 * g;
            fcA[kt] = mk4(msk * cp[0], msk * cp[1], msk * cp[2], msk * cp[3]);
        }
    }

    // ---- biases in D-layout (row = 16*mt + 4*g + r) ----
    f32x4 br, bz, bin, bhn, fcb4;
#pragma unroll
    for (int r = 0; r < 4; ++r) {
        const int oR = 16 * mtR + 4 * g + r;
        const int oZ = 16 * mtZ + 4 * g + r;
        const int oN = 16 * mtN + 4 * g + r;
        br[r]  = b_ih[oR] + b_hh[oR];
        bz[r]  = b_ih[oZ] + b_hh[oZ];
        bin[r] = b_ih[oN];
        bhn[r] = b_hh[oN];
        const int oF = 16 * w + 4 * g + r;
        fcb4[r] = (oF < 36) ? fc_b[oF] : 0.f;
    }

    float gamx[4], betx[4];
#pragma unroll
    for (int j = 0; j < 4; ++j) {
        const int k = 4 * g + j;
        gamx[j] = (k < 13) ? ln_gamma[k] : 0.f;
        betx[j] = (k < 13) ? ln_beta[k]  : 0.f;
    }

    // ---- state ----
    float pos0 = 0, pos1 = 0, pos2 = 0, vel0 = 0, vel1 = 0, vel2 = 0;
    float q0 = 1.0f, q1 = 0, q2 = 0, q3 = 0;
    f32x4 hstate = f32x4{0.f, 0.f, 0.f, 0.f};   // own h slice, exact f32
    f16x4 hB[4];                                // full h as B-fragments
#pragma unroll
    for (int i = 0; i < 4; ++i) hB[i] = mk4(0.f, 0.f, 0.f, 0.f);

    const float* ip = inputs + (size_t)e * TT * 9;
    float*       op = out    + (size_t)e * TT * 10;

    float cur[9];
#pragma unroll
    for (int k = 0; k < 9; ++k) cur[k] = ip[k];

    // dq for step 0 (input-only; hoisted off the head's critical chain)
    float dqw, dqx, dqy, dqz;
    {
        const float hx = cur[3] * 0.005f, hy = cur[4] * 0.005f, hz = cur[5] * 0.005f;
        const float dn = frsq(1.0f + hx * hx + hy * hy + hz * hz);
        dqw = dn; dqx = hx * dn; dqy = hy * dn; dqz = hz * dn;
    }

    for (int t = 0; t < TT; ++t) {
        // ---- Edit 1: whh MFMAs FIRST (hB = h_{t-1}).  Matrix pipe runs
        // under the scalar head below.
        f32x4 ar = br, az4 = bz, nhh = bhn;
#pragma unroll
        for (int kt = 0; kt < 4; ++kt) {
            ar  = mfma16(whhR[kt], hB[kt], ar);
            az4 = mfma16(whhZ[kt], hB[kt], az4);
            nhh = mfma16(whhN[kt], hB[kt], nhh);
        }

        const int tn = (t < TT - 1) ? (t + 1) : t;
        float nxt[9];
#pragma unroll
        for (int k = 0; k < 9; ++k) nxt[k] = ip[(size_t)tn * 9 + k];

        // dq for step t+1 (independent of state; fills stalls here)
        float dqwN, dqxN, dqyN, dqzN;
        {
            const float hx = nxt[3] * 0.005f, hy = nxt[4] * 0.005f, hz = nxt[5] * 0.005f;
            const float dn = frsq(1.0f + hx * hx + hy * hy + hz * hz);
            dqwN = dn; dqxN = hx * dn; dqyN = hy * dn; dqzN = hz * dn;
        }

        const float ax = cur[0], ay = cur[1], az = cur[2];
        const float mx = cur[6], my = cur[7], mz = cur[8];

        // q_pred = normalize(q * dq)   (dq precomputed)
        float qpw = q0 * dqw - q1 * dqx - q2 * dqy - q3 * dqz;
        float qpx = q0 * dqx + q1 * dqw + q2 * dqz - q3 * dqy;
        float qpy = q0 * dqy - q1 * dqz + q2 * dqw + q3 * dqx;
        float qpz = q0 * dqz + q1 * dqy - q2 * dqx + q3 * dqw;
        const float pn = frsq(qpw * qpw + qpx * qpx + qpy * qpy + qpz * qpz);
        qpw *= pn; qpx *= pn; qpy *= pn; qpz *= pn;

        // accel_world = R(q) @ accel - g   (old q)
        const float r00 = 1.0f - 2.0f * (q2 * q2 + q3 * q3);
        const float r01 = 2.0f * (q1 * q2 - q3 * q0);
        const float r02 = 2.0f * (q1 * q3 + q2 * q0);
        const float r10 = 2.0f * (q1 * q2 + q3 * q0);
        const float r11 = 1.0f - 2.0f * (q1 * q1 + q3 * q3);
        const float r12 = 2.0f * (q2 * q3 - q1 * q0);
        const float r20 = 2.0f * (q1 * q3 - q2 * q0);
        const float r21 = 2.0f * (q2 * q3 + q1 * q0);
        const float r22 = 1.0f - 2.0f * (q1 * q1 + q2 * q2);
        const float awx = r00 * ax + r01 * ay + r02 * az;
        const float awy = r10 * ax + r11 * ay + r12 * az;
        const float awz = r20 * ax + r21 * ay + r22 * az - 9.81f;

        const float vpx = vel0 + awx * 0.01f;
        const float vpy = vel1 + awy * 0.01f;
        const float vpz = vel2 + awz * 0.01f;
        const float ppx = pos0 + vel0 * 0.01f + awx * 5e-5f;
        const float ppy = pos1 + vel1 * 0.01f + awy * 5e-5f;
        const float ppz = pos2 + vel2 * 0.01f + awz * 5e-5f;

        // rows 0,2 of R(q_pred)
        const float s00 = 1.0f - 2.0f * (qpy * qpy + qpz * qpz);
        const float s01 = 2.0f * (qpx * qpy - qpz * qpw);
        const float s02 = 2.0f * (qpx * qpz + qpy * qpw);
        const float s20 = 2.0f * (qpx * qpz - qpy * qpw);
        const float s21 = 2.0f * (qpy * qpz + qpx * qpw);
        const float s22 = 1.0f - 2.0f * (qpx * qpx + qpy * qpy);
        const float gbx = 9.81f * s20, gby = 9.81f * s21, gbz = 9.81f * s22;
        const float mbx = 20.0f * s00 - 40.0f * s20;
        const float mby = 20.0f * s01 - 40.0f * s21;
        const float mbz = 20.0f * s02 - 40.0f * s22;

        float inn[6];
        inn[0] = mx - mbx; inn[1] = my - mby; inn[2] = mz - mbz;
        inn[3] = ax - gbx; inn[4] = ay - gby; inn[5] = az - gbz;

        float gin[13];
        gin[0] = inn[0]; gin[1] = inn[1]; gin[2] = inn[2];
        gin[3] = inn[3]; gin[4] = inn[4]; gin[5] = inn[5];
        gin[6] = vpx; gin[7] = vpy; gin[8] = vpz;
        gin[9] = qpw; gin[10] = qpx; gin[11] = qpy; gin[12] = qpz;

        // LayerNorm stats (f32)
        float mu = 0.0f;
#pragma unroll
        for (int k = 0; k < 13; ++k) mu += gin[k];
        mu *= (1.0f / 13.0f);
        float var = 0.0f;
#pragma unroll
        for (int k = 0; k < 13; ++k) { const float d = gin[k] - mu; var += d * d; }
        var *= (1.0f / 13.0f);
        const float sc = frsq(var + 1e-5f);

        // B-fragment of LN(gin): this lane supplies k = 4g..4g+3 of column bq
        const float xs0 = g == 0 ? gin[0] : g == 1 ? gin[4] : g == 2 ? gin[8]  : gin[12];
        const float xs1 = g == 0 ? gin[1] : g == 1 ? gin[5] : g == 2 ? gin[9]  : 0.f;
        const float xs2 = g == 0 ? gin[2] : g == 1 ? gin[6] : g == 2 ? gin[10] : 0.f;
        const float xs3 = g == 0 ? gin[3] : g == 1 ? gin[7] : g == 2 ? gin[11] : 0.f;
        const f16x4 xB = mk4((xs0 - mu) * sc * gamx[0] + betx[0],
                             (xs1 - mu) * sc * gamx[1] + betx[1],
                             (xs2 - mu) * sc * gamx[2] + betx[2],
                             (xs3 - mu) * sc * gamx[3] + betx[3]);

        // wih contribution last (accumulators already hold bias + whh terms)
        ar  = mfma16(wihR, xB, ar);
        az4 = mfma16(wihZ, xB, az4);
        const f32x4 nin = mfma16(wihN, xB, bin);

        // elementwise gates on own 4 rows; D-layout == next B-frag layout
        f32x4 hv = hstate;
#pragma unroll
        for (int r = 0; r < 4; ++r) {
            const float rr = sigm(ar[r]);
            const float zz = sigm(az4[r]);
            const float nn = tanh_fast(nin[r] + rr * nhh[r]);
            hv[r] = fmaf(zz, hv[r] - nn, nn);   // (1-z)*n + z*h
        }
        hstate = hv;
        const f16x4 hOwn = mk4(hv[0], hv[1], hv[2], hv[3]);

        // ---- cross-wave h exchange (wave w's D-frag == B-frag tile kt=w) ----
        s_h[w][lane] = __builtin_bit_cast(u32x2_t, hOwn);
        BARRIER();
#pragma unroll
        for (int kt = 0; kt < 4; ++kt)
            hB[kt] = __builtin_bit_cast(f16x4, s_h[kt][lane]);

        // ---- K = fc(h_new): waves 0..2, tile mt=w; 2x2 MFMA chains;
        //      b32 write form (mandatory - see header comment) ----
        if (w < 3) {
            const f32x4 zero4 = f32x4{0.f, 0.f, 0.f, 0.f};
            f32x4 a01 = mfma16(fcA[1], hB[1], mfma16(fcA[0], hB[0], fcb4));
            f32x4 a23 = mfma16(fcA[3], hB[3], mfma16(fcA[2], hB[2], zero4));
            const f32x4 a = a01 + a23;
            s_Kp[8 * w + 2 * g][bq]     = __builtin_bit_cast(unsigned int, pk16(a[0], a[1]));
            s_Kp[8 * w + 2 * g + 1][bq] = __builtin_bit_cast(unsigned int, pk16(a[2], a[3]));
        }
        BARRIER();

        // corr = K(6x6) @ innovation — b32 broadcast reads + 18 fdot2
        h2_t K2[18];
#pragma unroll
        for (int rp = 0; rp < 18; ++rp)
            K2[rp] = __builtin_bit_cast(h2_t, s_Kp[rp][bq]);

        const h2_t inn2_0 = pk16(inn[0], inn[1]);
        const h2_t inn2_1 = pk16(inn[2], inn[3]);
        const h2_t inn2_2 = pk16(inn[4], inn[5]);
        float c[6];
#pragma unroll
        for (int i = 0; i < 6; ++i)
            c[i] = fdot2(K2[3 * i + 0], inn2_0,
                   fdot2(K2[3 * i + 1], inn2_1,
                   fdot2(K2[3 * i + 2], inn2_2, 0.f)));

        pos0 = ppx + c[0]; pos1 = ppy + c[1]; pos2 = ppz + c[2];
        vel0 = vpx + c[3]; vel1 = vpy + c[4]; vel2 = vpz + c[5];
        q0 = qpw; q1 = qpx; q2 = qpy; q3 = qpz;
        dqw = dqwN; dqx = dqxN; dqy = dqyN; dqz = dqzN;

        // store: wave 0 only, group-split
        if (w == 0) {
            float* o0 = op + (size_t)t * 10;
            if (g == 0) {
                *(f32x4u*)(o0) = f32x4u{pos0, pos1, pos2, vel0};
            } else if (g == 1) {
                *(f32x4u*)(o0 + 4) = f32x4u{vel1, vel2, q0, q1};
            } else if (g == 2) {
                o0[8] = q2; o0[9] = q3;
            }
        }

#pragma unroll
        for (int k = 0; k < 9; ++k) cur[k] = nxt[k];
    }
}

extern "C" void kernel_launch(void* const* d_in, const int* in_sizes, int n_in,
                              void* d_out, int out_size, void* d_ws, size_t ws_size,
                              hipStream_t stream) {
    const float* inputs   = (const float*)d_in[0];
    const float* ln_gamma = (const float*)d_in[1];
    const float* ln_beta  = (const float*)d_in[2];
    const float* w_ih     = (const float*)d_in[3];
    const float* w_hh     = (const float*)d_in[4];
    const float* b_ih     = (const float*)d_in[5];
    const float* b_hh     = (const float*)d_in[6];
    const float* fc_w     = (const float*)d_in[7];
    const float* fc_b     = (const float*)d_in[8];
    float* out = (float*)d_out;

    const int B = in_sizes[0] / (TT * 9);
    kalman_kernel<<<dim3(B / 16), dim3(256), 0, stream>>>(
        inputs, ln_gamma, ln_beta, w_ih, w_hh, b_ih, b_hh, fc_w, fc_b, out);
}

// Round 13
// 704.213 us; speedup vs baseline: 1.2718x; 1.2718x over previous
//
#include <hip/hip_runtime.h>

#define TT 512

typedef _Float16 h2_t  __attribute__((ext_vector_type(2)));
typedef _Float16 f16x4 __attribute__((ext_vector_type(4)));
typedef float    f32x4 __attribute__((ext_vector_type(4)));
typedef float    f32x4u __attribute__((ext_vector_type(4), aligned(4)));
typedef unsigned int u32x2_t __attribute__((ext_vector_type(2)));

__device__ __forceinline__ float frcp(float x){ return __builtin_amdgcn_rcpf(x); }
__device__ __forceinline__ float frsq(float x){ return __builtin_amdgcn_rsqf(x); }
__device__ __forceinline__ float sigm(float x){ return frcp(1.0f + __expf(-x)); }
__device__ __forceinline__ float tanh_fast(float x){
    x = fminf(15.0f, fmaxf(-15.0f, x));
    float e = __expf(2.0f * x);
    return (e - 1.0f) * frcp(e + 1.0f);
}
__device__ __forceinline__ float fdot2(h2_t a, h2_t b, float c){
    return __builtin_amdgcn_fdot2(a, b, c, false);
}
__device__ __forceinline__ h2_t pk16(float a, float b){
    return __builtin_bit_cast(h2_t, __builtin_amdgcn_cvt_pkrtz(a, b));
}
__device__ __forceinline__ f16x4 mk4(float a, float b, float c, float d){
    u32x2_t u;
    u[0] = __builtin_bit_cast(unsigned int, pk16(a, b));
    u[1] = __builtin_bit_cast(unsigned int, pk16(c, d));
    return __builtin_bit_cast(f16x4, u);
}
__device__ __forceinline__ f32x4 mfma16(f16x4 a, f16x4 b, f32x4 c){
    return __builtin_amdgcn_mfma_f32_16x16x16f16(a, b, c, 0, 0, 0);
}

// lgkmcnt-only barrier (R9-verified, 630us).  Only cross-wave traffic is
// LDS; vmcnt drain (as in __syncthreads) is unnecessary.
#define BARRIER() do { asm volatile("s_waitcnt lgkmcnt(0)" ::: "memory"); \
                       __builtin_amdgcn_s_barrier();                      \
                       asm volatile("" ::: "memory"); } while (0)

// R9 KERNEL, VERBATIM (hardware-verified: 630.485 us, absmax 1.0).
// Session ledger: 2050 (R0 baseline) -> 1117 (R1 MFMA restructure) ->
// 660 (R2 4-wave M-split) -> 643 (R6 whh hoist) -> 630 (R9 lgkmcnt
// barrier).  Every neighborhood move from R9 regressed or failed:
//   R7 2-region pipeline      727 us  (head moved off whh overlap)
//   R8 bpermute K exchange    828 us  (60-cyc LDS-pipe chain post-barrier)
//   R10 deferred corr         700 us  (disturbed scheduler interleave)
//   R11 b64-packed K          FAIL    (4th deterministic b64-LDS failure)
//   R12 dq hoist + fc 2x2     833 us  (live-range growth broke schedule)
// HARD RULES (empirical): K exchange must be the b32 s_Kp[24][16] form
// (b64-packed writes fail deterministically: 264.5 / 206.0 absmax, 4
// fails vs 5 passes); no work motion across the barrier structure.
// Remaining idle (~45% at 1 wave/SIMD) is serial-recurrence dependent-
// chain latency + barrier skew; wave count is pinned at 1024 by
// batch 4096 / 16 elems-per-wave / 4-way M-split.  Practical floor.
//
// 4 waves/block, 16 batch elems/block, M-split: wave w owns h rows
// 16w..16w+15 (gate tiles {w,4+w,8+w}); 1024 waves = every SIMD occupied.
// Edit 1: whh MFMAs issue at loop top against hB=h_{t-1}; matrix pipe
// grinds under the ~250-op scalar head on the VALU pipe.
// h_new D-fragment of wave w IS B-fragment tile kt=w (row formula 16w+4g+r
// == k formula): the GRU recurrence needs no transpose.  Scalar phase
// replicates across waves; only wave 0 stores.
__global__
__attribute__((amdgpu_flat_work_group_size(256, 256), amdgpu_waves_per_eu(1, 1)))
void kalman_kernel(const float* __restrict__ inputs,
                   const float* __restrict__ ln_gamma,
                   const float* __restrict__ ln_beta,
                   const float* __restrict__ w_ih,
                   const float* __restrict__ w_hh,
                   const float* __restrict__ b_ih,
                   const float* __restrict__ b_hh,
                   const float* __restrict__ fc_w,
                   const float* __restrict__ fc_b,
                   float* __restrict__ out)
{
    __shared__ u32x2_t     s_h[4][64];    // h_new B-fragments, per kt tile
    __shared__ unsigned int s_Kp[24][16]; // K row-pairs (f16x2) x batch col

    const int tid  = threadIdx.x;
    const int lane = tid & 63;
    const int w    = tid >> 6;            // wave id = M-slice owner
    const int bq   = lane & 15;           // batch col / A row
    const int g    = lane >> 4;           // k-quad group
    const int e    = blockIdx.x * 16 + bq;

    const int mtR = w, mtZ = 4 + w, mtN = 8 + w;

    // ---- pinned A-fragments (f16), this wave's M-slice only ----
    f16x4 whhR[4], whhZ[4], whhN[4];
#pragma unroll
    for (int kt = 0; kt < 4; ++kt) {
        const float* rR = w_hh + (size_t)(16 * mtR + bq) * 64 + 16 * kt + 4 * g;
        const float* rZ = w_hh + (size_t)(16 * mtZ + bq) * 64 + 16 * kt + 4 * g;
        const float* rN = w_hh + (size_t)(16 * mtN + bq) * 64 + 16 * kt + 4 * g;
        whhR[kt] = mk4(rR[0], rR[1], rR[2], rR[3]);
        whhZ[kt] = mk4(rZ[0], rZ[1], rZ[2], rZ[3]);
        whhN[kt] = mk4(rN[0], rN[1], rN[2], rN[3]);
    }

    f16x4 wihR, wihZ, wihN;               // K=13 padded to 16
    {
        const float* rR = w_ih + (size_t)(16 * mtR + bq) * 13;
        const float* rZ = w_ih + (size_t)(16 * mtZ + bq) * 13;
        const float* rN = w_ih + (size_t)(16 * mtN + bq) * 13;
        const int k0 = 4 * g;
        const float m1 = (k0 + 1 < 13) ? 1.f : 0.f;
        const float m2 = (k0 + 2 < 13) ? 1.f : 0.f;
        const float m3 = (k0 + 3 < 13) ? 1.f : 0.f;
        wihR = mk4(rR[k0], m1 * rR[k0 + 1], m2 * rR[k0 + 2], m3 * rR[k0 + 3]);
        wihZ = mk4(rZ[k0], m1 * rZ[k0 + 1], m2 * rZ[k0 + 2], m3 * rZ[k0 + 3]);
        wihN = mk4(rN[k0], m1 * rN[k0 + 1], m2 * rN[k0 + 2], m3 * rN[k0 + 3]);
    }

    f16x4 fcA[4];                         // fc tile mt=w (rows >=36 masked)
    {
        const int o = 16 * w + bq;
        const float* rp = fc_w + (size_t)(o < 36 ? o : 0) * 64;
        const float msk = (o < 36) ? 1.f : 0.f;
#pragma unroll
        for (int kt = 0; kt < 4; ++kt) {
            const float* cp = rp + 16 * kt + 4 * g;
            fcA[kt] = mk4(msk * cp[0], msk * cp[1], msk * cp[2], msk * cp[3]);
        }
    }

    // ---- biases in D-layout (row = 16*mt + 4*g + r) ----
    f32x4 br, bz, bin, bhn, fcb4;
#pragma unroll
    for (int r = 0; r < 4; ++r) {
        const int oR = 16 * mtR + 4 * g + r;
        const int oZ = 16 * mtZ + 4 * g + r;
        const int oN = 16 * mtN + 4 * g + r;
        br[r]  = b_ih[oR] + b_hh[oR];
        bz[r]  = b_ih[oZ] + b_hh[oZ];
        bin[r] = b_ih[oN];
        bhn[r] = b_hh[oN];
        const int oF = 16 * w + 4 * g + r;
        fcb4[r] = (oF < 36) ? fc_b[oF] : 0.f;
    }

    float gamx[4], betx[4];
#pragma unroll
    for (int j = 0; j < 4; ++j) {
        const int k = 4 * g + j;
        gamx[j] = (k < 13) ? ln_gamma[k] : 0.f;
        betx[j] = (k < 13) ? ln_beta[k]  : 0.f;
    }

    // ---- state ----
    float pos0 = 0, pos1 = 0, pos2 = 0, vel0 = 0, vel1 = 0, vel2 = 0;
    float q0 = 1.0f, q1 = 0, q2 = 0, q3 = 0;
    f32x4 hstate = f32x4{0.f, 0.f, 0.f, 0.f};   // own h slice, exact f32
    f16x4 hB[4];                                // full h as B-fragments
#pragma unroll
    for (int i = 0; i < 4; ++i) hB[i] = mk4(0.f, 0.f, 0.f, 0.f);

    const float* ip = inputs + (size_t)e * TT * 9;
    float*       op = out    + (size_t)e * TT * 10;

    float cur[9];
#pragma unroll
    for (int k = 0; k < 9; ++k) cur[k] = ip[k];

    for (int t = 0; t < TT; ++t) {
        // ---- Edit 1: whh MFMAs FIRST (hB = h_{t-1}, unchanged until the
        // exchange).  Matrix pipe runs under the scalar head below.
        f32x4 ar = br, az4 = bz, nhh = bhn;
#pragma unroll
        for (int kt = 0; kt < 4; ++kt) {
            ar  = mfma16(whhR[kt], hB[kt], ar);
            az4 = mfma16(whhZ[kt], hB[kt], az4);
            nhh = mfma16(whhN[kt], hB[kt], nhh);
        }

        const int tn = (t < TT - 1) ? (t + 1) : t;
        float nxt[9];
#pragma unroll
        for (int k = 0; k < 9; ++k) nxt[k] = ip[(size_t)tn * 9 + k];

        const float ax = cur[0], ay = cur[1], az = cur[2];
        const float gx = cur[3], gy = cur[4], gz = cur[5];
        const float mx = cur[6], my = cur[7], mz = cur[8];

        // dq = normalize(1, gyro*dt/2); q_pred = normalize(q*dq)
        const float hx = gx * 0.005f, hy = gy * 0.005f, hz = gz * 0.005f;
        const float dn = frsq(1.0f + hx * hx + hy * hy + hz * hz);
        const float dw = dn, dx = hx * dn, dy = hy * dn, dz = hz * dn;
        float qpw = q0 * dw - q1 * dx - q2 * dy - q3 * dz;
        float qpx = q0 * dx + q1 * dw + q2 * dz - q3 * dy;
        float qpy = q0 * dy - q1 * dz + q2 * dw + q3 * dx;
        float qpz = q0 * dz + q1 * dy - q2 * dx + q3 * dw;
        const float pn = frsq(qpw * qpw + qpx * qpx + qpy * qpy + qpz * qpz);
        qpw *= pn; qpx *= pn; qpy *= pn; qpz *= pn;

        // accel_world = R(q) @ accel - g   (old q)
        const float r00 = 1.0f - 2.0f * (q2 * q2 + q3 * q3);
        const float r01 = 2.0f * (q1 * q2 - q3 * q0);
        const float r02 = 2.0f * (q1 * q3 + q2 * q0);
        const float r10 = 2.0f * (q1 * q2 + q3 * q0);
        const float r11 = 1.0f - 2.0f * (q1 * q1 + q3 * q3);
        const float r12 = 2.0f * (q2 * q3 - q1 * q0);
        const float r20 = 2.0f * (q1 * q3 - q2 * q0);
        const float r21 = 2.0f * (q2 * q3 + q1 * q0);
        const float r22 = 1.0f - 2.0f * (q1 * q1 + q2 * q2);
        const float awx = r00 * ax + r01 * ay + r02 * az;
        const float awy = r10 * ax + r11 * ay + r12 * az;
        const float awz = r20 * ax + r21 * ay + r22 * az - 9.81f;

        const float vpx = vel0 + awx * 0.01f;
        const float vpy = vel1 + awy * 0.01f;
        const float vpz = vel2 + awz * 0.01f;
        const float ppx = pos0 + vel0 * 0.01f + awx * 5e-5f;
        const float ppy = pos1 + vel1 * 0.01f + awy * 5e-5f;
        const float ppz = pos2 + vel2 * 0.01f + awz * 5e-5f;

        // rows 0,2 of R(q_pred)
        const float s00 = 1.0f - 2.0f * (qpy * qpy + qpz * qpz);
        const float s01 = 2.0f * (qpx * qpy - qpz * qpw);
        const float s02 = 2.0f * (qpx * qpz + qpy * qpw);
        const float s20 = 2.0f * (qpx * qpz - qpy * qpw);
        const float s21 = 2.0f * (qpy * qpz + qpx * qpw);
        const float s22 = 1.0f - 2.0f * (qpx * qpx + qpy * qpy);
        const float gbx = 9.81f * s20, gby = 9.81f * s21, gbz = 9.81f * s22;
        const float mbx = 20.0f * s00 - 40.0f * s20;
        const float mby = 20.0f * s01 - 40.0f * s21;
        const float mbz = 20.0f * s02 - 40.0f * s22;

        float inn[6];
        inn[0] = mx - mbx; inn[1] = my - mby; inn[2] = mz - mbz;
        inn[3] = ax - gbx; inn[4] = ay - gby; inn[5] = az - gbz;

        float gin[13];
        gin[0] = inn[0]; gin[1] = inn[1]; gin[2] = inn[2];
        gin[3] = inn[3]; gin[4] = inn[4]; gin[5] = inn[5];
        gin[6] = vpx; gin[7] = vpy; gin[8] = vpz;
        gin[9] = qpw; gin[10] = qpx; gin[11] = qpy; gin[12] = qpz;

        // LayerNorm stats (f32)
        float mu = 0.0f;
#pragma unroll
        for (int k = 0; k < 13; ++k) mu += gin[k];
        mu *= (1.0f / 13.0f);
        float var = 0.0f;
#pragma unroll
        for (int k = 0; k < 13; ++k) { const float d = gin[k] - mu; var += d * d; }
        var *= (1.0f / 13.0f);
        const float sc = frsq(var + 1e-5f);

        // B-fragment of LN(gin): this lane supplies k = 4g..4g+3 of column bq
        const float xs0 = g == 0 ? gin[0] : g == 1 ? gin[4] : g == 2 ? gin[8]  : gin[12];
        const float xs1 = g == 0 ? gin[1] : g == 1 ? gin[5] : g == 2 ? gin[9]  : 0.f;
        const float xs2 = g == 0 ? gin[2] : g == 1 ? gin[6] : g == 2 ? gin[10] : 0.f;
        const float xs3 = g == 0 ? gin[3] : g == 1 ? gin[7] : g == 2 ? gin[11] : 0.f;
        const f16x4 xB = mk4((xs0 - mu) * sc * gamx[0] + betx[0],
                             (xs1 - mu) * sc * gamx[1] + betx[1],
                             (xs2 - mu) * sc * gamx[2] + betx[2],
                             (xs3 - mu) * sc * gamx[3] + betx[3]);

        // wih contribution last (accumulators already hold bias + whh terms)
        ar  = mfma16(wihR, xB, ar);
        az4 = mfma16(wihZ, xB, az4);
        const f32x4 nin = mfma16(wihN, xB, bin);

        // elementwise gates on own 4 rows; D-layout == next B-frag layout
        f32x4 hv = hstate;
#pragma unroll
        for (int r = 0; r < 4; ++r) {
            const float rr = sigm(ar[r]);
            const float zz = sigm(az4[r]);
            const float nn = tanh_fast(nin[r] + rr * nhh[r]);
            hv[r] = fmaf(zz, hv[r] - nn, nn);   // (1-z)*n + z*h
        }
        hstate = hv;
        const f16x4 hOwn = mk4(hv[0], hv[1], hv[2], hv[3]);

        // ---- cross-wave h exchange (wave w's D-frag == B-frag tile kt=w) ----
        s_h[w][lane] = __builtin_bit_cast(u32x2_t, hOwn);
        BARRIER();
#pragma unroll
        for (int kt = 0; kt < 4; ++kt)
            hB[kt] = __builtin_bit_cast(f16x4, s_h[kt][lane]);

        // ---- K = fc(h_new): waves 0..2, tile mt=w ----
        if (w < 3) {
            f32x4 a = mfma16(fcA[0], hB[0], fcb4);
#pragma unroll
            for (int kt = 1; kt < 4; ++kt) a = mfma16(fcA[kt], hB[kt], a);
            s_Kp[8 * w + 2 * g][bq]     = __builtin_bit_cast(unsigned int, pk16(a[0], a[1]));
            s_Kp[8 * w + 2 * g + 1][bq] = __builtin_bit_cast(unsigned int, pk16(a[2], a[3]));
        }
        BARRIER();

        // corr = K(6x6) @ innovation — broadcast reads + 18 fdot2
        h2_t K2[18];
#pragma unroll
        for (int rp = 0; rp < 18; ++rp)
            K2[rp] = __builtin_bit_cast(h2_t, s_Kp[rp][bq]);

        const h2_t inn2_0 = pk16(inn[0], inn[1]);
        const h2_t inn2_1 = pk16(inn[2], inn[3]);
        const h2_t inn2_2 = pk16(inn[4], inn[5]);
        float c[6];
#pragma unroll
        for (int i = 0; i < 6; ++i)
            c[i] = fdot2(K2[3 * i + 0], inn2_0,
                   fdot2(K2[3 * i + 1], inn2_1,
                   fdot2(K2[3 * i + 2], inn2_2, 0.f)));

        pos0 = ppx + c[0]; pos1 = ppy + c[1]; pos2 = ppz + c[2];
        vel0 = vpx + c[3]; vel1 = vpy + c[4]; vel2 = vpz + c[5];
        q0 = qpw; q1 = qpx; q2 = qpy; q3 = qpz;

        // store: wave 0 only, group-split
        if (w == 0) {
            float* o0 = op + (size_t)t * 10;
            if (g == 0) {
                *(f32x4u*)(o0) = f32x4u{pos0, pos1, pos2, vel0};
            } else if (g == 1) {
                *(f32x4u*)(o0 + 4) = f32x4u{vel1, vel2, q0, q1};
            } else if (g == 2) {
                o0[8] = q2; o0[9] = q3;
            }
        }

#pragma unroll
        for (int k = 0; k < 9; ++k) cur[k] = nxt[k];
    }
}

extern "C" void kernel_launch(void* const* d_in, const int* in_sizes, int n_in,
                              void* d_out, int out_size, void* d_ws, size_t ws_size,
                              hipStream_t stream) {
    const float* inputs   = (const float*)d_in[0];
    const float* ln_gamma = (const float*)d_in[1];
    const float* ln_beta  = (const float*)d_in[2];
    const float* w_ih     = (const float*)d_in[3];
    const float* w_hh     = (const float*)d_in[4];
    const float* b_ih     = (const float*)d_in[5];
    const float* b_hh     = (const float*)d_in[6];
    const float* fc_w     = (const float*)d_in[7];
    const float* fc_b     = (const float*)d_in[8];
    float* out = (float*)d_out;

    const int B = in_sizes[0] / (TT * 9);
    kalman_kernel<<<dim3(B / 16), dim3(64 * 4), 0, stream>>>(
        inputs, ln_gamma, ln_beta, w_ih, w_hh, b_ih, b_hh, fc_w, fc_b, out);
}